// Round 1
// baseline (751.007 us; speedup 1.0000x reference)
//
#include <hip/hip_runtime.h>
#include <math.h>

// ---------------- problem constants ----------------
#define B_DIM   4
#define S_DIM   4096
#define D_DIM   2048
#define DFF_DIM 8192
#define K_TOP   512
#define M_ROWS  (B_DIM * K_TOP)   // 2048 selected rows total

typedef _Float16 half8 __attribute__((ext_vector_type(8)));
typedef _Float16 half4 __attribute__((ext_vector_type(4)));
typedef float    floatx4 __attribute__((ext_vector_type(4)));

// ---------------- workspace layout (bytes) ----------------
// logits [B*S] f32 | tokens [B*k] i32 | rw [B*k] f32 | fx [2048][2048] f16
// W1T [8192][2048] f16 | W2T [2048][8192] f16 | h [2048][8192] f16
static const size_t OFF_LOGITS = 0;
static const size_t OFF_TOK    = 65536;
static const size_t OFF_RW     = 73728;
static const size_t OFF_FX     = 81920;
static const size_t OFF_W1T    = OFF_FX  + (size_t)M_ROWS * D_DIM * 2;      //  +8 MiB
static const size_t OFF_W2T    = OFF_W1T + (size_t)DFF_DIM * D_DIM * 2;     // +32 MiB
static const size_t OFF_H      = OFF_W2T + (size_t)D_DIM * DFF_DIM * 2;     // +32 MiB
static const size_t WS_NEEDED  = OFF_H   + (size_t)M_ROWS * DFF_DIM * 2;    // +32 MiB  (~104 MiB)

// ---------------- helpers ----------------
__device__ __forceinline__ void async_ld16(const void* g, void* l) {
  // 16B direct global->LDS; LDS dest = wave-uniform base + lane*16
  __builtin_amdgcn_global_load_lds((const __attribute__((address_space(1))) unsigned int*)g,
                                   (__attribute__((address_space(3))) unsigned int*)l,
                                   16, 0, 0);
}

// ---------------- router logits: one wave per token row ----------------
__global__ __launch_bounds__(256) void router_logits(const float* __restrict__ x,
                                                     const float* __restrict__ Wr,
                                                     const float* __restrict__ br,
                                                     float* __restrict__ logits) {
  int row  = blockIdx.x * 4 + (threadIdx.x >> 6);
  int lane = threadIdx.x & 63;
  const float4* xr = (const float4*)(x + (size_t)row * D_DIM);
  const float4* wr = (const float4*)Wr;
  float s = 0.f;
#pragma unroll
  for (int i = 0; i < (D_DIM / 4) / 64; ++i) {     // 8 float4 per lane
    float4 a = xr[lane + i * 64];
    float4 w = wr[lane + i * 64];
    s += a.x * w.x + a.y * w.y + a.z * w.z + a.w * w.w;
  }
#pragma unroll
  for (int off = 32; off > 0; off >>= 1) s += __shfl_down(s, off, 64);
  if (lane == 0) logits[row] = s + br[0];
}

// ---------------- top-k (one block per batch): radix-select + ordered compaction + softmax ----------------
__global__ __launch_bounds__(256) void topk_select(const float* __restrict__ logits,
                                                   int* __restrict__ tokens,
                                                   float* __restrict__ rw) {
  int b = blockIdx.x;
  const float* lg = logits + (size_t)b * S_DIM;
  __shared__ unsigned int keys[S_DIM];
  __shared__ unsigned int bins[256];
  __shared__ unsigned int scan[256];
  __shared__ unsigned int sh_prefix, sh_r, sh_cgt, baseG, baseE;
  __shared__ float sel_logit[K_TOP];
  __shared__ float red[8];

  int tid = threadIdx.x;
  for (int s = tid; s < S_DIM; s += 256) {
    unsigned int u = __float_as_uint(lg[s]);
    keys[s] = (u & 0x80000000u) ? ~u : (u | 0x80000000u);   // order-preserving key
  }
  if (tid == 0) { sh_prefix = 0u; sh_r = K_TOP; sh_cgt = 0u; baseG = 0u; baseE = 0u; }
  __syncthreads();

  // MSB radix select: exact key of the K_TOP-th largest (duplicate-safe)
  for (int p = 24; p >= 0; p -= 8) {
    bins[tid] = 0u;
    __syncthreads();
    unsigned int prefix = sh_prefix;
    unsigned int maskhi = (p == 24) ? 0u : (0xFFFFFFFFu << (p + 8));
    for (int s = tid; s < S_DIM; s += 256) {
      unsigned int kk = keys[s];
      if ((kk & maskhi) == prefix) atomicAdd(&bins[(kk >> p) & 255u], 1u);
    }
    __syncthreads();
    if (tid == 0) {
      unsigned int r = sh_r; int bsel = 0;
      for (int bi = 255; bi >= 0; --bi) {
        if (bins[bi] >= r) { bsel = bi; break; }
        r -= bins[bi];
      }
      sh_r = r;
      sh_prefix = prefix | ((unsigned int)bsel << p);
    }
    __syncthreads();
  }
  unsigned int T = sh_prefix;

  // count strictly-greater
  unsigned int cg = 0;
  for (int s = tid; s < S_DIM; s += 256) if (keys[s] > T) cg++;
  atomicAdd(&sh_cgt, cg);
  __syncthreads();
  unsigned int need_eq = (unsigned int)K_TOP - sh_cgt;   // ties broken by lowest index (matches lax.top_k)

  // ordered compaction: tokens emitted in ascending index order (= reference's sorted tokens)
  for (int chunk = 0; chunk < S_DIM; chunk += 256) {
    int s = chunk + tid;
    unsigned int kk = keys[s];
    unsigned int fG = (kk > T) ? 1u : 0u;
    unsigned int fE = (kk == T) ? 1u : 0u;
    scan[tid] = fG | (fE << 16);
    __syncthreads();
#pragma unroll
    for (int off = 1; off < 256; off <<= 1) {
      unsigned int add = (tid >= off) ? scan[tid - off] : 0u;
      __syncthreads();
      scan[tid] += add;
      __syncthreads();
    }
    unsigned int incl = scan[tid];
    unsigned int exG = (incl & 0xFFFFu) - fG;
    unsigned int exE = (incl >> 16) - fE;
    unsigned int gBefore = baseG + exG;
    unsigned int eBefore = baseE + exE;
    bool sel = fG || (fE && (eBefore < need_eq));
    if (sel) {
      unsigned int eTaken = (eBefore < need_eq) ? eBefore : need_eq;
      unsigned int pos = gBefore + eTaken;
      tokens[b * K_TOP + (int)pos] = s;
      sel_logit[pos] = lg[s];
    }
    __syncthreads();
    if (tid == 255) { baseG += (incl & 0xFFFFu); baseE += (incl >> 16); }
    __syncthreads();
  }

  // softmax over the selected logits
  int lane = tid & 63, wv = tid >> 6;
  float mx = -1e30f;
  for (int i = tid; i < K_TOP; i += 256) mx = fmaxf(mx, sel_logit[i]);
#pragma unroll
  for (int off = 32; off > 0; off >>= 1) mx = fmaxf(mx, __shfl_down(mx, off, 64));
  if (lane == 0) red[wv] = mx;
  __syncthreads();
  if (tid == 0) red[0] = fmaxf(fmaxf(red[0], red[1]), fmaxf(red[2], red[3]));
  __syncthreads();
  float M = red[0];
  float sm = 0.f;
  for (int i = tid; i < K_TOP; i += 256) sm += expf(sel_logit[i] - M);
#pragma unroll
  for (int off = 32; off > 0; off >>= 1) sm += __shfl_down(sm, off, 64);
  if (lane == 0) red[4 + wv] = sm;
  __syncthreads();
  if (tid == 0) red[4] = red[4] + red[5] + red[6] + red[7];
  __syncthreads();
  float SUM = red[4];
  for (int i = tid; i < K_TOP; i += 256) rw[b * K_TOP + i] = expf(sel_logit[i] - M) / SUM;
}

// ---------------- transpose + f32->f16 convert: in[K][N] -> out[N][K] ----------------
__global__ __launch_bounds__(256) void transpose_cvt(const float* __restrict__ in,
                                                     _Float16* __restrict__ out,
                                                     int K, int N) {
  __shared__ float tile[32][33];
  int nb = blockIdx.x * 32, kb = blockIdx.y * 32;
  int tx = threadIdx.x, ty = threadIdx.y;
#pragma unroll
  for (int i = ty; i < 32; i += 8)
    tile[i][tx] = in[(size_t)(kb + i) * N + (nb + tx)];
  __syncthreads();
#pragma unroll
  for (int i = ty; i < 32; i += 8)
    out[(size_t)(nb + i) * K + (kb + tx)] = (_Float16)tile[tx][i];
}

// ---------------- gather selected rows of x -> f16 fx [M_ROWS][D] ----------------
__global__ __launch_bounds__(256) void gather_cvt(const float* __restrict__ x,
                                                  const int* __restrict__ tokens,
                                                  _Float16* __restrict__ fx) {
  int row = blockIdx.x;            // 0..2047
  int b = row >> 9;
  int token = tokens[row];
  const float4* src = (const float4*)(x + ((size_t)b * S_DIM + token) * D_DIM);
  half4* dst = (half4*)(fx + (size_t)row * D_DIM);
  for (int i = threadIdx.x; i < D_DIM / 4; i += 256) {
    float4 v = src[i];
    half4 o;
    o[0] = (_Float16)v.x; o[1] = (_Float16)v.y; o[2] = (_Float16)v.z; o[3] = (_Float16)v.w;
    dst[i] = o;
  }
}

// ---------------- m97-style f16 GEMM, C = A @ Bt^T (+ fused epilogue) ----------------
// A [M][K] f16, Bt [N][K] f16.  BM=BN=128, BK=32, 256 thr (4 waves), wave tile 64x64.
// EPI 0: h = f16(gelu(C + bias))   EPI 1: out[b,token,:] = x[b,token,:] + rw*(C + bias)
template <int EPI>
__global__ __launch_bounds__(256) void gemm_bt(const _Float16* __restrict__ A,
                                               const _Float16* __restrict__ Bt,
                                               const float* __restrict__ bias,
                                               _Float16* __restrict__ Ch,
                                               const int* __restrict__ tokens,
                                               const float* __restrict__ rwp,
                                               const float* __restrict__ x,
                                               float* __restrict__ outp,
                                               int M, int N, int K) {
  __shared__ _Float16 As[128 * 32];
  __shared__ _Float16 Bs[128 * 32];
  const int tid = threadIdx.x;
  const int lane = tid & 63;
  const int wave = tid >> 6;
  const int bm = blockIdx.y * 128;
  const int bn = blockIdx.x * 128;
  const int wm = (wave & 1) * 64;
  const int wn = (wave >> 1) * 64;
  const int mr = lane & 15;
  const int kq = (lane >> 4) * 8;

  floatx4 acc[4][4] = {};

  for (int kt = 0; kt < K; kt += 32) {
#pragma unroll
    for (int j = 0; j < 2; ++j) {
      int c = (wave * 2 + j) * 64 + lane;      // 16B chunk id in tile
      int m  = c >> 2;
      int k8 = (c & 3) * 8;
      async_ld16(A  + (size_t)(bm + m) * K + kt + k8, As + (size_t)(wave * 2 + j) * 512);
      async_ld16(Bt + (size_t)(bn + m) * K + kt + k8, Bs + (size_t)(wave * 2 + j) * 512);
    }
    __syncthreads();   // drains vmcnt: LDS tiles ready

    half8 af[4], bf[4];
#pragma unroll
    for (int i = 0; i < 4; ++i) af[i] = *(const half8*)(As + (wm + i * 16 + mr) * 32 + kq);
#pragma unroll
    for (int j = 0; j < 4; ++j) bf[j] = *(const half8*)(Bs + (wn + j * 16 + mr) * 32 + kq);
#pragma unroll
    for (int i = 0; i < 4; ++i)
#pragma unroll
      for (int j = 0; j < 4; ++j)
        acc[i][j] = __builtin_amdgcn_mfma_f32_16x16x32_f16(af[i], bf[j], acc[i][j], 0, 0, 0);
    __syncthreads();   // protect LDS before next stage
  }

  const int r0 = (lane >> 4) * 4;
  const int cn = lane & 15;
  if (EPI == 0) {
#pragma unroll
    for (int i = 0; i < 4; ++i)
#pragma unroll
      for (int j = 0; j < 4; ++j) {
        int col = bn + wn + j * 16 + cn;
        float bv = bias[col];
#pragma unroll
        for (int r = 0; r < 4; ++r) {
          int row = bm + wm + i * 16 + r0 + r;
          float v = acc[i][j][r] + bv;
          v = 0.5f * v * (1.0f + erff(v * 0.7071067811865475f));   // exact GELU
          Ch[(size_t)row * N + col] = (_Float16)v;
        }
      }
  } else {
#pragma unroll
    for (int i = 0; i < 4; ++i) {
      int rowb = bm + wm + i * 16 + r0;
#pragma unroll
      for (int r = 0; r < 4; ++r) {
        int row = rowb + r;
        int bb = row >> 9;
        int token = tokens[row];
        float wgt = rwp[row];
        size_t base = ((size_t)bb * S_DIM + token) * D_DIM;
#pragma unroll
        for (int j = 0; j < 4; ++j) {
          int col = bn + wn + j * 16 + cn;
          float v = acc[i][j][r] + bias[col];
          outp[base + col] = x[base + col] + wgt * v;
        }
      }
    }
  }
}

// ---------------- launch ----------------
extern "C" void kernel_launch(void* const* d_in, const int* in_sizes, int n_in,
                              void* d_out, int out_size, void* d_ws, size_t ws_size,
                              hipStream_t stream) {
  const float* x  = (const float*)d_in[0];
  const float* Wr = (const float*)d_in[1];
  const float* br = (const float*)d_in[2];
  const float* W1 = (const float*)d_in[3];
  const float* b1 = (const float*)d_in[4];
  const float* W2 = (const float*)d_in[5];
  const float* b2 = (const float*)d_in[6];
  float* out = (float*)d_out;

  if (ws_size < WS_NEEDED) return;   // fail loudly (poisoned out) rather than corrupt

  char* ws = (char*)d_ws;
  float*     logits = (float*)(ws + OFF_LOGITS);
  int*       tokens = (int*)(ws + OFF_TOK);
  float*     rw     = (float*)(ws + OFF_RW);
  _Float16*  fx     = (_Float16*)(ws + OFF_FX);
  _Float16*  W1T    = (_Float16*)(ws + OFF_W1T);
  _Float16*  W2T    = (_Float16*)(ws + OFF_W2T);
  _Float16*  h      = (_Float16*)(ws + OFF_H);

  // out = x (scatter rows overwritten later, same stream => ordered)
  hipMemcpyAsync(out, x, (size_t)B_DIM * S_DIM * D_DIM * sizeof(float),
                 hipMemcpyDeviceToDevice, stream);

  // weights: [K][N] f32 -> [N][K] f16
  transpose_cvt<<<dim3(DFF_DIM / 32, D_DIM / 32), dim3(32, 8), 0, stream>>>(W1, W1T, D_DIM, DFF_DIM);
  transpose_cvt<<<dim3(D_DIM / 32, DFF_DIM / 32), dim3(32, 8), 0, stream>>>(W2, W2T, DFF_DIM, D_DIM);

  router_logits<<<(B_DIM * S_DIM) / 4, 256, 0, stream>>>(x, Wr, br, logits);
  topk_select<<<B_DIM, 256, 0, stream>>>(logits, tokens, rw);
  gather_cvt<<<M_ROWS, 256, 0, stream>>>(x, tokens, fx);

  // h = gelu(fx @ W1 + b1)
  gemm_bt<0><<<dim3(DFF_DIM / 128, M_ROWS / 128), 256, 0, stream>>>(
      fx, W1T, b1, h, nullptr, nullptr, nullptr, nullptr, M_ROWS, DFF_DIM, D_DIM);
  // out[b,tok,:] = x[b,tok,:] + rw * (h @ W2 + b2)
  gemm_bt<1><<<dim3(D_DIM / 128, M_ROWS / 128), 256, 0, stream>>>(
      h, W2T, b2, nullptr, tokens, rw, x, out, M_ROWS, D_DIM, DFF_DIM);
}

// Round 2
// 625.601 us; speedup vs baseline: 1.2005x; 1.2005x over previous
//
#include <hip/hip_runtime.h>
#include <math.h>

// ---------------- problem constants ----------------
#define B_DIM   4
#define S_DIM   4096
#define D_DIM   2048
#define DFF_DIM 8192
#define K_TOP   512
#define M_ROWS  (B_DIM * K_TOP)   // 2048 selected rows total
#define NSPLIT  4                 // split-K factor for gemm2

typedef _Float16 half8 __attribute__((ext_vector_type(8)));
typedef _Float16 half4 __attribute__((ext_vector_type(4)));
typedef float    floatx4 __attribute__((ext_vector_type(4)));

// ---------------- workspace layout (bytes) ----------------
// logits [B*S] f32 | tokens [B*k] i32 | rw [B*k] f32 | fx [2048][2048] f16
// W1T [8192][2048] f16 | W2T [2048][8192] f16 | h [2048][8192] f16
// partials (gemm2 split-K, f16 [4][2048][2048] = 32 MiB) overlay W1T (dead after gemm1).
static const size_t OFF_LOGITS = 0;
static const size_t OFF_TOK    = 65536;
static const size_t OFF_RW     = 73728;
static const size_t OFF_FX     = 81920;
static const size_t OFF_W1T    = OFF_FX  + (size_t)M_ROWS * D_DIM * 2;      //  +8 MiB
static const size_t OFF_W2T    = OFF_W1T + (size_t)DFF_DIM * D_DIM * 2;     // +32 MiB
static const size_t OFF_H      = OFF_W2T + (size_t)D_DIM * DFF_DIM * 2;     // +32 MiB
static const size_t WS_NEEDED  = OFF_H   + (size_t)M_ROWS * DFF_DIM * 2;    // +32 MiB  (~104 MiB)
static const size_t OFF_PART   = OFF_W1T;  // overlay

// ---------------- helpers ----------------
__device__ __forceinline__ void async_ld16(const void* g, void* l) {
  // 16B direct global->LDS; LDS dest = wave-uniform base + lane*16
  __builtin_amdgcn_global_load_lds((const __attribute__((address_space(1))) unsigned int*)g,
                                   (__attribute__((address_space(3))) unsigned int*)l,
                                   16, 0, 0);
}

// ---------------- router logits: one wave per token row ----------------
__global__ __launch_bounds__(256) void router_logits(const float* __restrict__ x,
                                                     const float* __restrict__ Wr,
                                                     const float* __restrict__ br,
                                                     float* __restrict__ logits) {
  int row  = blockIdx.x * 4 + (threadIdx.x >> 6);
  int lane = threadIdx.x & 63;
  const float4* xr = (const float4*)(x + (size_t)row * D_DIM);
  const float4* wr = (const float4*)Wr;
  float s = 0.f;
#pragma unroll
  for (int i = 0; i < (D_DIM / 4) / 64; ++i) {     // 8 float4 per lane
    float4 a = xr[lane + i * 64];
    float4 w = wr[lane + i * 64];
    s += a.x * w.x + a.y * w.y + a.z * w.z + a.w * w.w;
  }
#pragma unroll
  for (int off = 32; off > 0; off >>= 1) s += __shfl_down(s, off, 64);
  if (lane == 0) logits[row] = s + br[0];
}

// ---------------- top-k (one block per batch) ----------------
// MSB radix select with PARALLEL suffix-scan bin selection, then a single
// 256-thread scan compaction (each thread owns 16 contiguous indices so the
// emitted token order is ascending-index = reference's sorted order).
__global__ __launch_bounds__(256) void topk_select(const float* __restrict__ logits,
                                                   int* __restrict__ tokens,
                                                   float* __restrict__ rw) {
  int b = blockIdx.x;
  const float* lg = logits + (size_t)b * S_DIM;
  __shared__ unsigned int keys[S_DIM];
  __shared__ unsigned int bins[256];
  __shared__ unsigned int sscan[256];
  __shared__ unsigned int sh_prefix, sh_r;
  __shared__ float sel_logit[K_TOP];
  __shared__ float red[8];

  int tid = threadIdx.x;
  for (int s = tid; s < S_DIM; s += 256) {
    unsigned int u = __float_as_uint(lg[s]);
    keys[s] = (u & 0x80000000u) ? ~u : (u | 0x80000000u);   // order-preserving key
  }
  if (tid == 0) { sh_prefix = 0u; sh_r = K_TOP; }
  __syncthreads();

  // 4 radix passes: exact key of the K_TOP-th largest (duplicate-safe)
  for (int p = 24; p >= 0; p -= 8) {
    bins[tid] = 0u;
    __syncthreads();
    unsigned int prefix = sh_prefix;
    unsigned int maskhi = (p == 24) ? 0u : (0xFFFFFFFFu << (p + 8));
    for (int s = tid; s < S_DIM; s += 256) {
      unsigned int kk = keys[s];
      if ((kk & maskhi) == prefix) atomicAdd(&bins[(kk >> p) & 255u], 1u);
    }
    __syncthreads();
    // suffix counts: sscan[i] = sum(bins[255-i .. 255])
    sscan[tid] = bins[255 - tid];
    __syncthreads();
#pragma unroll
    for (int off = 1; off < 256; off <<= 1) {
      unsigned int v = (tid >= off) ? sscan[tid - off] : 0u;
      __syncthreads();
      sscan[tid] += v;
      __syncthreads();
    }
    unsigned int r = sh_r;
    unsigned int above = (tid > 0) ? sscan[tid - 1] : 0u;
    bool hit = (sscan[tid] >= r) && (above < r);   // exactly one thread
    __syncthreads();
    if (hit) {
      sh_prefix = prefix | ((unsigned int)(255 - tid) << p);
      sh_r = r - above;
    }
    __syncthreads();
  }
  unsigned int T = sh_prefix;

  // single-scan ordered compaction: thread owns indices [tid*16, tid*16+16)
  int s0 = tid * 16;
  unsigned int g = 0, e = 0;
#pragma unroll
  for (int j = 0; j < 16; ++j) {
    unsigned int kk = keys[s0 + j];
    g += (kk > T);
    e += (kk == T);
  }
  sscan[tid] = g | (e << 16);
  __syncthreads();
#pragma unroll
  for (int off = 1; off < 256; off <<= 1) {
    unsigned int v = (tid >= off) ? sscan[tid - off] : 0u;
    __syncthreads();
    sscan[tid] += v;
    __syncthreads();
  }
  unsigned int incl = sscan[tid];
  unsigned int Gtot = sscan[255] & 0xFFFFu;
  unsigned int need = (unsigned int)K_TOP - Gtot;      // ties: lowest index (stable, matches lax.top_k)
  unsigned int gr = (incl & 0xFFFFu) - g;
  unsigned int er = (incl >> 16) - e;
#pragma unroll
  for (int j = 0; j < 16; ++j) {
    unsigned int kk = keys[s0 + j];
    if (kk > T) {
      unsigned int pos = gr + (er < need ? er : need);
      tokens[b * K_TOP + (int)pos] = s0 + j;
      sel_logit[pos] = __uint_as_float((kk & 0x80000000u) ? (kk & 0x7FFFFFFFu) : ~kk);
      gr++;
    } else if (kk == T) {
      if (er < need) {
        unsigned int pos = gr + er;
        tokens[b * K_TOP + (int)pos] = s0 + j;
        sel_logit[pos] = __uint_as_float((kk & 0x80000000u) ? (kk & 0x7FFFFFFFu) : ~kk);
      }
      er++;
    }
  }
  __syncthreads();

  // softmax over the selected logits
  int lane = tid & 63, wv = tid >> 6;
  float mx = -1e30f;
  for (int i = tid; i < K_TOP; i += 256) mx = fmaxf(mx, sel_logit[i]);
#pragma unroll
  for (int off = 32; off > 0; off >>= 1) mx = fmaxf(mx, __shfl_down(mx, off, 64));
  if (lane == 0) red[wv] = mx;
  __syncthreads();
  if (tid == 0) red[0] = fmaxf(fmaxf(red[0], red[1]), fmaxf(red[2], red[3]));
  __syncthreads();
  float M = red[0];
  float sm = 0.f;
  for (int i = tid; i < K_TOP; i += 256) sm += expf(sel_logit[i] - M);
#pragma unroll
  for (int off = 32; off > 0; off >>= 1) sm += __shfl_down(sm, off, 64);
  if (lane == 0) red[4 + wv] = sm;
  __syncthreads();
  if (tid == 0) red[4] = red[4] + red[5] + red[6] + red[7];
  __syncthreads();
  float SUM = red[4];
  for (int i = tid; i < K_TOP; i += 256) rw[b * K_TOP + i] = expf(sel_logit[i] - M) / SUM;
}

// ---------------- transpose + f32->f16 convert: in[K][N] -> out[N][K] ----------------
// 64x64 tiles; float4 coalesced reads, half8 (16B) coalesced writes.
__global__ __launch_bounds__(256) void transpose_cvt(const float* __restrict__ in,
                                                     _Float16* __restrict__ out,
                                                     int K, int N) {
  __shared__ float tile[64][65];
  int nb = blockIdx.x * 64, kb = blockIdx.y * 64;
  int tid = threadIdx.x;
  int lr = tid >> 4;            // 0..15
  int lc = (tid & 15) * 4;      // col offset
#pragma unroll
  for (int p = 0; p < 4; ++p) {
    int row = p * 16 + lr;
    float4 v = *(const float4*)(in + (size_t)(kb + row) * N + nb + lc);
    tile[row][lc] = v.x; tile[row][lc + 1] = v.y; tile[row][lc + 2] = v.z; tile[row][lc + 3] = v.w;
  }
  __syncthreads();
#pragma unroll
  for (int p = 0; p < 2; ++p) {
    int cc = p * 256 + tid;
    int n  = cc >> 3;           // 0..63
    int kc = (cc & 7) * 8;
    half8 o;
#pragma unroll
    for (int j = 0; j < 8; ++j) o[j] = (_Float16)tile[kc + j][n];
    *(half8*)(out + (size_t)(nb + n) * K + kb + kc) = o;
  }
}

// ---------------- gather selected rows of x -> f16 fx [M_ROWS][D] ----------------
__global__ __launch_bounds__(256) void gather_cvt(const float* __restrict__ x,
                                                  const int* __restrict__ tokens,
                                                  _Float16* __restrict__ fx) {
  int row = blockIdx.x;            // 0..2047
  int b = row >> 9;
  int token = tokens[row];
  const float4* src = (const float4*)(x + ((size_t)b * S_DIM + token) * D_DIM);
  half4* dst = (half4*)(fx + (size_t)row * D_DIM);
  for (int i = threadIdx.x; i < D_DIM / 4; i += 256) {
    float4 v = src[i];
    half4 o;
    o[0] = (_Float16)v.x; o[1] = (_Float16)v.y; o[2] = (_Float16)v.z; o[3] = (_Float16)v.w;
    dst[i] = o;
  }
}

// ---------------- m97-style f16 GEMM, C = A @ Bt^T ----------------
// A [M][K] f16, Bt [N][K] f16.  BM=BN=128, BK=32, 256 thr (4 waves), wave tile 64x64.
// LDS layout XOR-swizzled: element (m, kgroup g) at halves offset m*32 + (g^((m>>1)&3))*8.
// Each 16-lane b128 read group then covers all eight 4-bank groups exactly twice -> 2-way (free).
// EPI 0: h = f16(gelu(C + bias))   EPI 2: f16 split-K partial store (bias deferred to reduce)
template <int EPI>
__global__ __launch_bounds__(256) void gemm_bt(const _Float16* __restrict__ A,
                                               const _Float16* __restrict__ Bt,
                                               const float* __restrict__ bias,
                                               _Float16* __restrict__ Co,
                                               int M, int N, int K, int Kspan) {
  __shared__ _Float16 As[128 * 32];
  __shared__ _Float16 Bs[128 * 32];
  const int tid = threadIdx.x;
  const int lane = tid & 63;
  const int wave = tid >> 6;
  const int bm = blockIdx.y * 128;
  const int bn = blockIdx.x * 128;
  const int wm = (wave & 1) * 64;
  const int wn = (wave >> 1) * 64;
  const int mr = lane & 15;
  const int sw = (((lane >> 4) ^ ((lane >> 1) & 3))) * 8;   // swizzled k-offset (halves)
  const int k0 = blockIdx.z * Kspan;

  floatx4 acc[4][4] = {};

  for (int kt = k0; kt < k0 + Kspan; kt += 32) {
#pragma unroll
    for (int j = 0; j < 2; ++j) {
      int c = (wave * 2 + j) * 64 + lane;      // 16B chunk slot in tile
      int m  = c >> 2;
      int g  = (c & 3) ^ ((m >> 1) & 3);       // swizzled k-group to fetch
      async_ld16(A  + (size_t)(bm + m) * K + kt + g * 8, As + (size_t)(wave * 2 + j) * 512);
      async_ld16(Bt + (size_t)(bn + m) * K + kt + g * 8, Bs + (size_t)(wave * 2 + j) * 512);
    }
    __syncthreads();   // drains vmcnt: LDS tiles ready

    half8 af[4], bf[4];
#pragma unroll
    for (int i = 0; i < 4; ++i) af[i] = *(const half8*)(As + (wm + i * 16 + mr) * 32 + sw);
#pragma unroll
    for (int j = 0; j < 4; ++j) bf[j] = *(const half8*)(Bs + (wn + j * 16 + mr) * 32 + sw);
#pragma unroll
    for (int i = 0; i < 4; ++i)
#pragma unroll
      for (int j = 0; j < 4; ++j)
        acc[i][j] = __builtin_amdgcn_mfma_f32_16x16x32_f16(af[i], bf[j], acc[i][j], 0, 0, 0);
    __syncthreads();   // protect LDS before next stage
  }

  const int r0 = (lane >> 4) * 4;
  const int cn = lane & 15;
  if (EPI == 0) {
#pragma unroll
    for (int i = 0; i < 4; ++i)
#pragma unroll
      for (int j = 0; j < 4; ++j) {
        int col = bn + wn + j * 16 + cn;
        float bv = bias[col];
#pragma unroll
        for (int r = 0; r < 4; ++r) {
          int row = bm + wm + i * 16 + r0 + r;
          float v = acc[i][j][r] + bv;
          v = 0.5f * v * (1.0f + erff(v * 0.7071067811865475f));   // exact GELU
          Co[(size_t)row * N + col] = (_Float16)v;
        }
      }
  } else {
    // split-K partial: Co[(kz*M + row)*N + col]
    size_t zoff = (size_t)blockIdx.z * M;
#pragma unroll
    for (int i = 0; i < 4; ++i)
#pragma unroll
      for (int j = 0; j < 4; ++j) {
        int col = bn + wn + j * 16 + cn;
#pragma unroll
        for (int r = 0; r < 4; ++r) {
          int row = bm + wm + i * 16 + r0 + r;
          Co[(zoff + row) * N + col] = (_Float16)acc[i][j][r];
        }
      }
  }
}

// ---------------- split-K reduce + bias + router-weight + scatter-add ----------------
// out already == x (copy). One block per selected row; coalesced row RMW.
__global__ __launch_bounds__(256) void reduce_scatter(const _Float16* __restrict__ part,
                                                      const float* __restrict__ bias,
                                                      const int* __restrict__ tokens,
                                                      const float* __restrict__ rw,
                                                      float* __restrict__ out) {
  int m = blockIdx.x;
  int b = m >> 9;
  int token = tokens[m];
  float wgt = rw[m];
  float* orow = out + ((size_t)b * S_DIM + token) * D_DIM;
  int c = threadIdx.x * 8;
  float acc[8] = {0, 0, 0, 0, 0, 0, 0, 0};
#pragma unroll
  for (int kz = 0; kz < NSPLIT; ++kz) {
    half8 p = *(const half8*)(part + ((size_t)kz * M_ROWS + m) * D_DIM + c);
#pragma unroll
    for (int j = 0; j < 8; ++j) acc[j] += (float)p[j];
  }
  float4 o0 = *(const float4*)(orow + c);
  float4 o1 = *(const float4*)(orow + c + 4);
  float4 b0 = *(const float4*)(bias + c);
  float4 b1 = *(const float4*)(bias + c + 4);
  o0.x += wgt * (acc[0] + b0.x);
  o0.y += wgt * (acc[1] + b0.y);
  o0.z += wgt * (acc[2] + b0.z);
  o0.w += wgt * (acc[3] + b0.w);
  o1.x += wgt * (acc[4] + b1.x);
  o1.y += wgt * (acc[5] + b1.y);
  o1.z += wgt * (acc[6] + b1.z);
  o1.w += wgt * (acc[7] + b1.w);
  *(float4*)(orow + c)     = o0;
  *(float4*)(orow + c + 4) = o1;
}

// ---------------- launch ----------------
extern "C" void kernel_launch(void* const* d_in, const int* in_sizes, int n_in,
                              void* d_out, int out_size, void* d_ws, size_t ws_size,
                              hipStream_t stream) {
  const float* x  = (const float*)d_in[0];
  const float* Wr = (const float*)d_in[1];
  const float* br = (const float*)d_in[2];
  const float* W1 = (const float*)d_in[3];
  const float* b1 = (const float*)d_in[4];
  const float* W2 = (const float*)d_in[5];
  const float* b2 = (const float*)d_in[6];
  float* out = (float*)d_out;

  if (ws_size < WS_NEEDED) return;   // fail loudly (poisoned out) rather than corrupt

  char* ws = (char*)d_ws;
  float*     logits = (float*)(ws + OFF_LOGITS);
  int*       tokens = (int*)(ws + OFF_TOK);
  float*     rw     = (float*)(ws + OFF_RW);
  _Float16*  fx     = (_Float16*)(ws + OFF_FX);
  _Float16*  W1T    = (_Float16*)(ws + OFF_W1T);
  _Float16*  W2T    = (_Float16*)(ws + OFF_W2T);
  _Float16*  h      = (_Float16*)(ws + OFF_H);
  _Float16*  part   = (_Float16*)(ws + OFF_PART);   // overlays W1T (dead after gemm1)

  // out = x (scatter rows updated in-place later; same stream => ordered)
  hipMemcpyAsync(out, x, (size_t)B_DIM * S_DIM * D_DIM * sizeof(float),
                 hipMemcpyDeviceToDevice, stream);

  // weights: [K][N] f32 -> [N][K] f16
  transpose_cvt<<<dim3(DFF_DIM / 64, D_DIM / 64), 256, 0, stream>>>(W1, W1T, D_DIM, DFF_DIM);
  transpose_cvt<<<dim3(D_DIM / 64, DFF_DIM / 64), 256, 0, stream>>>(W2, W2T, DFF_DIM, D_DIM);

  router_logits<<<(B_DIM * S_DIM) / 4, 256, 0, stream>>>(x, Wr, br, logits);
  topk_select<<<B_DIM, 256, 0, stream>>>(logits, tokens, rw);
  gather_cvt<<<M_ROWS, 256, 0, stream>>>(x, tokens, fx);

  // h = gelu(fx @ W1 + b1)
  gemm_bt<0><<<dim3(DFF_DIM / 128, M_ROWS / 128, 1), 256, 0, stream>>>(
      fx, W1T, b1, h, M_ROWS, DFF_DIM, D_DIM, D_DIM);
  // partials[kz] = h @ W2 (K-chunk kz)
  gemm_bt<2><<<dim3(D_DIM / 128, M_ROWS / 128, NSPLIT), 256, 0, stream>>>(
      h, W2T, nullptr, part, M_ROWS, D_DIM, DFF_DIM, DFF_DIM / NSPLIT);
  // out[b,tok,:] += rw * (sum partials + b2)
  reduce_scatter<<<M_ROWS, 256, 0, stream>>>(part, b2, tokens, rw, out);
}

// Round 3
// 600.686 us; speedup vs baseline: 1.2502x; 1.0415x over previous
//
#include <hip/hip_runtime.h>
#include <math.h>

// ---------------- problem constants ----------------
#define B_DIM   4
#define S_DIM   4096
#define D_DIM   2048
#define DFF_DIM 8192
#define K_TOP   512
#define M_ROWS  (B_DIM * K_TOP)   // 2048 selected rows total
#define NSPLIT  4                 // split-K factor for gemm2

typedef _Float16 half8 __attribute__((ext_vector_type(8)));
typedef _Float16 half4 __attribute__((ext_vector_type(4)));
typedef float    floatx4 __attribute__((ext_vector_type(4)));

// ---------------- workspace layout (bytes) ----------------
// logits [B*S] f32 (64KB; selmap int32 OVERLAYS it - logits dead after topk key-load)
// tokens [B*k] i32 | rw [B*k] f32 | fx [2048][2048] f16
// W1T [8192][2048] f16 | W2T [2048][8192] f16 | h [2048][8192] f16
// partials (gemm2 split-K, f16 [4][2048][2048] = 32 MiB) overlay W1T (dead after gemm1).
static const size_t OFF_LOGITS = 0;
static const size_t OFF_SELMAP = 0;        // overlay (see topk_select)
static const size_t OFF_TOK    = 65536;
static const size_t OFF_RW     = 73728;
static const size_t OFF_FX     = 81920;
static const size_t OFF_W1T    = OFF_FX  + (size_t)M_ROWS * D_DIM * 2;      //  +8 MiB
static const size_t OFF_W2T    = OFF_W1T + (size_t)DFF_DIM * D_DIM * 2;     // +32 MiB
static const size_t OFF_H      = OFF_W2T + (size_t)D_DIM * DFF_DIM * 2;     // +32 MiB
static const size_t WS_NEEDED  = OFF_H   + (size_t)M_ROWS * DFF_DIM * 2;    // +32 MiB  (~104 MiB)
static const size_t OFF_PART   = OFF_W1T;  // overlay

// ---------------- helpers ----------------
__device__ __forceinline__ void async_ld16(const void* g, void* l) {
  // 16B direct global->LDS; LDS dest = wave-uniform base + lane*16
  __builtin_amdgcn_global_load_lds((const __attribute__((address_space(1))) unsigned int*)g,
                                   (__attribute__((address_space(3))) unsigned int*)l,
                                   16, 0, 0);
}

// gfx9 waitcnt imm: vm[3:0]+[15:14], exp[6:4], lgkm[11:8]
#define WAITCNT_VM4   0x0F74   // vmcnt(4), exp/lgkm ignored
#define WAITCNT_VM0   0x0F70   // vmcnt(0), exp/lgkm ignored
#define WAITCNT_LGKM0 0xC07F   // lgkmcnt(0), vm/exp ignored

// ---------------- router logits: one wave per token row ----------------
__global__ __launch_bounds__(256) void router_logits(const float* __restrict__ x,
                                                     const float* __restrict__ Wr,
                                                     const float* __restrict__ br,
                                                     float* __restrict__ logits) {
  int row  = blockIdx.x * 4 + (threadIdx.x >> 6);
  int lane = threadIdx.x & 63;
  const float4* xr = (const float4*)(x + (size_t)row * D_DIM);
  const float4* wr = (const float4*)Wr;
  float s = 0.f;
#pragma unroll
  for (int i = 0; i < (D_DIM / 4) / 64; ++i) {     // 8 float4 per lane
    float4 a = xr[lane + i * 64];
    float4 w = wr[lane + i * 64];
    s += a.x * w.x + a.y * w.y + a.z * w.z + a.w * w.w;
  }
#pragma unroll
  for (int off = 32; off > 0; off >>= 1) s += __shfl_down(s, off, 64);
  if (lane == 0) logits[row] = s + br[0];
}

// ---------------- top-k (one block per batch) ----------------
// MSB radix select with parallel suffix-scan bin selection, single-scan ordered
// compaction. Also writes selmap[b*S+s] = selected-slot-or--1 (OVERLAYS logits:
// per-thread aliasing is safe - thread t only ever touches s == t (mod 256)).
__global__ __launch_bounds__(256) void topk_select(const float* logits,
                                                   int* selmap,
                                                   int* __restrict__ tokens,
                                                   float* __restrict__ rw) {
  int b = blockIdx.x;
  const float* lg = logits + (size_t)b * S_DIM;
  __shared__ unsigned int keys[S_DIM];
  __shared__ unsigned int bins[256];
  __shared__ unsigned int sscan[256];
  __shared__ unsigned int sh_prefix, sh_r;
  __shared__ float sel_logit[K_TOP];
  __shared__ float red[8];

  int tid = threadIdx.x;
  for (int s = tid; s < S_DIM; s += 256) {
    unsigned int u = __float_as_uint(lg[s]);
    keys[s] = (u & 0x80000000u) ? ~u : (u | 0x80000000u);   // order-preserving key
    selmap[b * S_DIM + s] = -1;   // aliases lg[s]: same thread, read-then-write
  }
  if (tid == 0) { sh_prefix = 0u; sh_r = K_TOP; }
  __syncthreads();

  // 4 radix passes: exact key of the K_TOP-th largest (duplicate-safe)
  for (int p = 24; p >= 0; p -= 8) {
    bins[tid] = 0u;
    __syncthreads();
    unsigned int prefix = sh_prefix;
    unsigned int maskhi = (p == 24) ? 0u : (0xFFFFFFFFu << (p + 8));
    for (int s = tid; s < S_DIM; s += 256) {
      unsigned int kk = keys[s];
      if ((kk & maskhi) == prefix) atomicAdd(&bins[(kk >> p) & 255u], 1u);
    }
    __syncthreads();
    sscan[tid] = bins[255 - tid];
    __syncthreads();
#pragma unroll
    for (int off = 1; off < 256; off <<= 1) {
      unsigned int v = (tid >= off) ? sscan[tid - off] : 0u;
      __syncthreads();
      sscan[tid] += v;
      __syncthreads();
    }
    unsigned int r = sh_r;
    unsigned int above = (tid > 0) ? sscan[tid - 1] : 0u;
    bool hit = (sscan[tid] >= r) && (above < r);   // exactly one thread
    __syncthreads();
    if (hit) {
      sh_prefix = prefix | ((unsigned int)(255 - tid) << p);
      sh_r = r - above;
    }
    __syncthreads();
  }
  unsigned int T = sh_prefix;

  // single-scan ordered compaction: thread owns indices [tid*16, tid*16+16)
  int s0 = tid * 16;
  unsigned int g = 0, e = 0;
#pragma unroll
  for (int j = 0; j < 16; ++j) {
    unsigned int kk = keys[s0 + j];
    g += (kk > T);
    e += (kk == T);
  }
  sscan[tid] = g | (e << 16);
  __syncthreads();
#pragma unroll
  for (int off = 1; off < 256; off <<= 1) {
    unsigned int v = (tid >= off) ? sscan[tid - off] : 0u;
    __syncthreads();
    sscan[tid] += v;
    __syncthreads();
  }
  unsigned int incl = sscan[tid];
  unsigned int Gtot = sscan[255] & 0xFFFFu;
  unsigned int need = (unsigned int)K_TOP - Gtot;      // ties: lowest index (matches lax.top_k)
  unsigned int gr = (incl & 0xFFFFu) - g;
  unsigned int er = (incl >> 16) - e;
#pragma unroll
  for (int j = 0; j < 16; ++j) {
    unsigned int kk = keys[s0 + j];
    if (kk > T) {
      unsigned int pos = gr + (er < need ? er : need);
      tokens[b * K_TOP + (int)pos] = s0 + j;
      sel_logit[pos] = __uint_as_float((kk & 0x80000000u) ? (kk & 0x7FFFFFFFu) : ~kk);
      selmap[b * S_DIM + s0 + j] = (int)pos;
      gr++;
    } else if (kk == T) {
      if (er < need) {
        unsigned int pos = gr + er;
        tokens[b * K_TOP + (int)pos] = s0 + j;
        sel_logit[pos] = __uint_as_float((kk & 0x80000000u) ? (kk & 0x7FFFFFFFu) : ~kk);
        selmap[b * S_DIM + s0 + j] = (int)pos;
      }
      er++;
    }
  }
  __syncthreads();

  // softmax over the selected logits
  int lane = tid & 63, wv = tid >> 6;
  float mx = -1e30f;
  for (int i = tid; i < K_TOP; i += 256) mx = fmaxf(mx, sel_logit[i]);
#pragma unroll
  for (int off = 32; off > 0; off >>= 1) mx = fmaxf(mx, __shfl_down(mx, off, 64));
  if (lane == 0) red[wv] = mx;
  __syncthreads();
  if (tid == 0) red[0] = fmaxf(fmaxf(red[0], red[1]), fmaxf(red[2], red[3]));
  __syncthreads();
  float M = red[0];
  float sm = 0.f;
  for (int i = tid; i < K_TOP; i += 256) sm += expf(sel_logit[i] - M);
#pragma unroll
  for (int off = 32; off > 0; off >>= 1) sm += __shfl_down(sm, off, 64);
  if (lane == 0) red[4 + wv] = sm;
  __syncthreads();
  if (tid == 0) red[4] = red[4] + red[5] + red[6] + red[7];
  __syncthreads();
  float SUM = red[4];
  for (int i = tid; i < K_TOP; i += 256) rw[b * K_TOP + i] = expf(sel_logit[i] - M) / SUM;
}

// ---------------- transpose + f32->f16 convert: in[K][N] -> out[N][K] ----------------
__global__ __launch_bounds__(256) void transpose_cvt(const float* __restrict__ in,
                                                     _Float16* __restrict__ out,
                                                     int K, int N) {
  __shared__ float tile[64][65];
  int nb = blockIdx.x * 64, kb = blockIdx.y * 64;
  int tid = threadIdx.x;
  int lr = tid >> 4;            // 0..15
  int lc = (tid & 15) * 4;      // col offset
#pragma unroll
  for (int p = 0; p < 4; ++p) {
    int row = p * 16 + lr;
    float4 v = *(const float4*)(in + (size_t)(kb + row) * N + nb + lc);
    tile[row][lc] = v.x; tile[row][lc + 1] = v.y; tile[row][lc + 2] = v.z; tile[row][lc + 3] = v.w;
  }
  __syncthreads();
#pragma unroll
  for (int p = 0; p < 2; ++p) {
    int cc = p * 256 + tid;
    int n  = cc >> 3;           // 0..63
    int kc = (cc & 7) * 8;
    half8 o;
#pragma unroll
    for (int j = 0; j < 8; ++j) o[j] = (_Float16)tile[kc + j][n];
    *(half8*)(out + (size_t)(nb + n) * K + kb + kc) = o;
  }
}

// ---------------- gather selected rows of x -> f16 fx [M_ROWS][D] ----------------
__global__ __launch_bounds__(256) void gather_cvt(const float* __restrict__ x,
                                                  const int* __restrict__ tokens,
                                                  _Float16* __restrict__ fx) {
  int row = blockIdx.x;            // 0..2047
  int b = row >> 9;
  int token = tokens[row];
  const float4* src = (const float4*)(x + ((size_t)b * S_DIM + token) * D_DIM);
  half4* dst = (half4*)(fx + (size_t)row * D_DIM);
  for (int i = threadIdx.x; i < D_DIM / 4; i += 256) {
    float4 v = src[i];
    half4 o;
    o[0] = (_Float16)v.x; o[1] = (_Float16)v.y; o[2] = (_Float16)v.z; o[3] = (_Float16)v.w;
    dst[i] = o;
  }
}

// ---------------- f16 GEMM, C = A @ Bt^T, double-buffered DMA K-loop ----------------
// A [M][K] f16, Bt [N][K] f16.  BM=BN=128, BK=32, 256 thr (4 waves), wave tile 64x64.
// XOR-swizzled LDS (verified conflict-free in R2). Raw s_barrier + vmcnt(4):
// next tile's 4 DMA loads/wave are issued BEFORE waiting on current tile's ->
// DMA latency overlaps a full iteration instead of sitting on the barrier drain.
// EPI 0: Co = f16(gelu(C + bias))   EPI 2: f16 split-K partial (bias deferred)
template <int EPI>
__global__ __launch_bounds__(256) void gemm_bt(const _Float16* __restrict__ A,
                                               const _Float16* __restrict__ Bt,
                                               const float* __restrict__ bias,
                                               _Float16* __restrict__ Co,
                                               int M, int N, int K, int Kspan) {
  __shared__ _Float16 As[2][128 * 32];
  __shared__ _Float16 Bs[2][128 * 32];
  const int tid = threadIdx.x;
  const int lane = tid & 63;
  const int wave = tid >> 6;
  const int bm = blockIdx.y * 128;
  const int bn = blockIdx.x * 128;
  const int wm = (wave & 1) * 64;
  const int wn = (wave >> 1) * 64;
  const int mr = lane & 15;
  const int sw = ((lane >> 4) ^ ((lane >> 1) & 3)) * 8;   // swizzled k-offset (halves)
  const int k0 = blockIdx.z * Kspan;
  const int kend = k0 + Kspan;

  // per-wave DMA sources (2 A-chunks + 2 B-chunks per tile)
  const int c0 = (wave * 2) * 64 + lane;
  const int c1 = (wave * 2 + 1) * 64 + lane;
  const int m0 = c0 >> 2, g0 = (c0 & 3) ^ ((m0 >> 1) & 3);
  const int m1 = c1 >> 2, g1 = (c1 & 3) ^ ((m1 >> 1) & 3);
  const _Float16* a0p = A  + (size_t)(bm + m0) * K + g0 * 8;
  const _Float16* a1p = A  + (size_t)(bm + m1) * K + g1 * 8;
  const _Float16* b0p = Bt + (size_t)(bn + m0) * K + g0 * 8;
  const _Float16* b1p = Bt + (size_t)(bn + m1) * K + g1 * 8;
  const int slot0 = (wave * 2) * 512;
  const int slot1 = (wave * 2 + 1) * 512;

  floatx4 acc[4][4] = {};

  // prologue: tile k0 -> buf 0
  async_ld16(a0p + k0, &As[0][slot0]);
  async_ld16(b0p + k0, &Bs[0][slot0]);
  async_ld16(a1p + k0, &As[0][slot1]);
  async_ld16(b1p + k0, &Bs[0][slot1]);

  for (int kt = k0; kt < kend; kt += 64) {
    // ---- stage 0: prefetch kt+32 -> buf1, compute buf0 (tile kt) ----
    {
      int kn = kt + 32;   // always < kend (Kspan multiple of 64)
      async_ld16(a0p + kn, &As[1][slot0]);
      async_ld16(b0p + kn, &Bs[1][slot0]);
      async_ld16(a1p + kn, &As[1][slot1]);
      async_ld16(b1p + kn, &Bs[1][slot1]);
      __builtin_amdgcn_s_waitcnt(WAITCNT_VM4);   // tile-kt DMAs landed
    }
    __builtin_amdgcn_s_barrier();
    {
      half8 af[4], bf[4];
#pragma unroll
      for (int i = 0; i < 4; ++i) af[i] = *(const half8*)(&As[0][(wm + i * 16 + mr) * 32 + sw]);
#pragma unroll
      for (int j = 0; j < 4; ++j) bf[j] = *(const half8*)(&Bs[0][(wn + j * 16 + mr) * 32 + sw]);
#pragma unroll
      for (int i = 0; i < 4; ++i)
#pragma unroll
        for (int j = 0; j < 4; ++j)
          acc[i][j] = __builtin_amdgcn_mfma_f32_16x16x32_f16(af[i], bf[j], acc[i][j], 0, 0, 0);
    }
    __builtin_amdgcn_s_waitcnt(WAITCNT_LGKM0);   // my ds_reads complete before...
    __builtin_amdgcn_s_barrier();                // ...anyone overwrites buf0

    // ---- stage 1: prefetch kt+64 -> buf0 (if any), compute buf1 (tile kt+32) ----
    if (kt + 64 < kend) {
      int kn = kt + 64;
      async_ld16(a0p + kn, &As[0][slot0]);
      async_ld16(b0p + kn, &Bs[0][slot0]);
      async_ld16(a1p + kn, &As[0][slot1]);
      async_ld16(b1p + kn, &Bs[0][slot1]);
      __builtin_amdgcn_s_waitcnt(WAITCNT_VM4);
    } else {
      __builtin_amdgcn_s_waitcnt(WAITCNT_VM0);
    }
    __builtin_amdgcn_s_barrier();
    {
      half8 af[4], bf[4];
#pragma unroll
      for (int i = 0; i < 4; ++i) af[i] = *(const half8*)(&As[1][(wm + i * 16 + mr) * 32 + sw]);
#pragma unroll
      for (int j = 0; j < 4; ++j) bf[j] = *(const half8*)(&Bs[1][(wn + j * 16 + mr) * 32 + sw]);
#pragma unroll
      for (int i = 0; i < 4; ++i)
#pragma unroll
        for (int j = 0; j < 4; ++j)
          acc[i][j] = __builtin_amdgcn_mfma_f32_16x16x32_f16(af[i], bf[j], acc[i][j], 0, 0, 0);
    }
    __builtin_amdgcn_s_waitcnt(WAITCNT_LGKM0);
    __builtin_amdgcn_s_barrier();
  }

  const int r0 = (lane >> 4) * 4;
  const int cn = lane & 15;
  if (EPI == 0) {
#pragma unroll
    for (int i = 0; i < 4; ++i)
#pragma unroll
      for (int j = 0; j < 4; ++j) {
        int col = bn + wn + j * 16 + cn;
        float bv = bias[col];
#pragma unroll
        for (int r = 0; r < 4; ++r) {
          int row = bm + wm + i * 16 + r0 + r;
          float v = acc[i][j][r] + bv;
          v = 0.5f * v * (1.0f + erff(v * 0.7071067811865475f));   // exact GELU
          Co[(size_t)row * N + col] = (_Float16)v;
        }
      }
  } else {
    size_t zoff = (size_t)blockIdx.z * M;
#pragma unroll
    for (int i = 0; i < 4; ++i)
#pragma unroll
      for (int j = 0; j < 4; ++j) {
        int col = bn + wn + j * 16 + cn;
#pragma unroll
        for (int r = 0; r < 4; ++r) {
          int row = bm + wm + i * 16 + r0 + r;
          Co[(zoff + row) * N + col] = (_Float16)acc[i][j][r];
        }
      }
  }
}

// ---------------- finalize: out = x everywhere; selected rows += rw*(sum partials + b2) ----
// Replaces the early 128 MiB memcpy (which thrashed LLC before the GEMMs) AND
// the separate row-RMW reduce_scatter. One block per (b,s) row.
__global__ __launch_bounds__(256) void finalize(const float* __restrict__ x,
                                                const _Float16* __restrict__ part,
                                                const float* __restrict__ bias,
                                                const int* __restrict__ selmap,
                                                const float* __restrict__ rw,
                                                float* __restrict__ out) {
  int row = blockIdx.x;                 // 0 .. B*S-1
  size_t base = (size_t)row * D_DIM;
  int sel = selmap[row];
  int c = threadIdx.x * 8;
  float4 o0 = *(const float4*)(x + base + c);
  float4 o1 = *(const float4*)(x + base + c + 4);
  if (sel >= 0) {
    float wgt = rw[sel];
    float acc[8] = {0, 0, 0, 0, 0, 0, 0, 0};
#pragma unroll
    for (int kz = 0; kz < NSPLIT; ++kz) {
      half8 p = *(const half8*)(part + ((size_t)kz * M_ROWS + sel) * D_DIM + c);
#pragma unroll
      for (int j = 0; j < 8; ++j) acc[j] += (float)p[j];
    }
    float4 b0 = *(const float4*)(bias + c);
    float4 b1 = *(const float4*)(bias + c + 4);
    o0.x += wgt * (acc[0] + b0.x);
    o0.y += wgt * (acc[1] + b0.y);
    o0.z += wgt * (acc[2] + b0.z);
    o0.w += wgt * (acc[3] + b0.w);
    o1.x += wgt * (acc[4] + b1.x);
    o1.y += wgt * (acc[5] + b1.y);
    o1.z += wgt * (acc[6] + b1.z);
    o1.w += wgt * (acc[7] + b1.w);
  }
  *(float4*)(out + base + c)     = o0;
  *(float4*)(out + base + c + 4) = o1;
}

// ---------------- launch ----------------
extern "C" void kernel_launch(void* const* d_in, const int* in_sizes, int n_in,
                              void* d_out, int out_size, void* d_ws, size_t ws_size,
                              hipStream_t stream) {
  const float* x  = (const float*)d_in[0];
  const float* Wr = (const float*)d_in[1];
  const float* br = (const float*)d_in[2];
  const float* W1 = (const float*)d_in[3];
  const float* b1 = (const float*)d_in[4];
  const float* W2 = (const float*)d_in[5];
  const float* b2 = (const float*)d_in[6];
  float* out = (float*)d_out;

  if (ws_size < WS_NEEDED) return;   // fail loudly (poisoned out) rather than corrupt

  char* ws = (char*)d_ws;
  float*     logits = (float*)(ws + OFF_LOGITS);
  int*       selmap = (int*)(ws + OFF_SELMAP);     // overlays logits
  int*       tokens = (int*)(ws + OFF_TOK);
  float*     rw     = (float*)(ws + OFF_RW);
  _Float16*  fx     = (_Float16*)(ws + OFF_FX);
  _Float16*  W1T    = (_Float16*)(ws + OFF_W1T);
  _Float16*  W2T    = (_Float16*)(ws + OFF_W2T);
  _Float16*  h      = (_Float16*)(ws + OFF_H);
  _Float16*  part   = (_Float16*)(ws + OFF_PART);  // overlays W1T (dead after gemm1)

  // weights: [K][N] f32 -> [N][K] f16
  transpose_cvt<<<dim3(DFF_DIM / 64, D_DIM / 64), 256, 0, stream>>>(W1, W1T, D_DIM, DFF_DIM);
  transpose_cvt<<<dim3(D_DIM / 64, DFF_DIM / 64), 256, 0, stream>>>(W2, W2T, DFF_DIM, D_DIM);

  router_logits<<<(B_DIM * S_DIM) / 4, 256, 0, stream>>>(x, Wr, br, logits);
  topk_select<<<B_DIM, 256, 0, stream>>>(logits, selmap, tokens, rw);
  gather_cvt<<<M_ROWS, 256, 0, stream>>>(x, tokens, fx);

  // h = gelu(fx @ W1 + b1)
  gemm_bt<0><<<dim3(DFF_DIM / 128, M_ROWS / 128, 1), 256, 0, stream>>>(
      fx, W1T, b1, h, M_ROWS, DFF_DIM, D_DIM, D_DIM);
  // partials[kz] = h @ W2 (K-chunk kz)
  gemm_bt<2><<<dim3(D_DIM / 128, M_ROWS / 128, NSPLIT), 256, 0, stream>>>(
      h, W2T, nullptr, part, M_ROWS, D_DIM, DFF_DIM, DFF_DIM / NSPLIT);
  // out = x; selected rows += rw * (sum partials + b2)
  finalize<<<B_DIM * S_DIM, 256, 0, stream>>>(x, part, b2, selmap, rw, out);
}